// Round 3
// baseline (550.960 us; speedup 1.0000x reference)
//
#include <hip/hip_runtime.h>
#include <math.h>

// Problem constants (match reference)
#define BB 1024
#define TT 2048
#define II 2
#define HH 64

// ---- inline-asm building blocks -------------------------------------------
// RL: broadcast h[k] (lane k of v80) into an SGPR.
// FM: acc += h[k] * w[k]   (SGPR src0, VGPR src1 — 1 scalar read: legal)
// ML: acc  = h[k] * w[k]   (first touch of accs 1..3, saves zero-init movs)
#define RL(s,k)   "v_readlane_b32 " s ", v80, " k "\n\t"
#define FM(a,s,w) "v_fmac_f32 " a ", " s ", " w "\n\t"
#define ML(a,s,w) "v_mul_f32 "  a ", " s ", " w "\n\t"

// 64 MACs: weights w[k] = v(12+k); SGPR banks A=s20-27, B=s28-35 ping-pong so
// every readlane->consume distance is >= 8 instructions (SGPR-write hazard).
// acc for k is v(76 + (k&3)) -> 4 independent FMA chains.
#define MACBLOCK \
 RL("s20","0") RL("s21","1") RL("s22","2") RL("s23","3") \
 RL("s24","4") RL("s25","5") RL("s26","6") RL("s27","7") \
 RL("s28","8")  FM("v76","s20","v12") \
 RL("s29","9")  ML("v77","s21","v13") \
 RL("s30","10") ML("v78","s22","v14") \
 RL("s31","11") ML("v79","s23","v15") \
 RL("s32","12") FM("v76","s24","v16") \
 RL("s33","13") FM("v77","s25","v17") \
 RL("s34","14") FM("v78","s26","v18") \
 RL("s35","15") FM("v79","s27","v19") \
 RL("s20","16") FM("v76","s28","v20") \
 RL("s21","17") FM("v77","s29","v21") \
 RL("s22","18") FM("v78","s30","v22") \
 RL("s23","19") FM("v79","s31","v23") \
 RL("s24","20") FM("v76","s32","v24") \
 RL("s25","21") FM("v77","s33","v25") \
 RL("s26","22") FM("v78","s34","v26") \
 RL("s27","23") FM("v79","s35","v27") \
 RL("s28","24") FM("v76","s20","v28") \
 RL("s29","25") FM("v77","s21","v29") \
 RL("s30","26") FM("v78","s22","v30") \
 RL("s31","27") FM("v79","s23","v31") \
 RL("s32","28") FM("v76","s24","v32") \
 RL("s33","29") FM("v77","s25","v33") \
 RL("s34","30") FM("v78","s26","v34") \
 RL("s35","31") FM("v79","s27","v35") \
 RL("s20","32") FM("v76","s28","v36") \
 RL("s21","33") FM("v77","s29","v37") \
 RL("s22","34") FM("v78","s30","v38") \
 RL("s23","35") FM("v79","s31","v39") \
 RL("s24","36") FM("v76","s32","v40") \
 RL("s25","37") FM("v77","s33","v41") \
 RL("s26","38") FM("v78","s34","v42") \
 RL("s27","39") FM("v79","s35","v43") \
 RL("s28","40") FM("v76","s20","v44") \
 RL("s29","41") FM("v77","s21","v45") \
 RL("s30","42") FM("v78","s22","v46") \
 RL("s31","43") FM("v79","s23","v47") \
 RL("s32","44") FM("v76","s24","v48") \
 RL("s33","45") FM("v77","s25","v49") \
 RL("s34","46") FM("v78","s26","v50") \
 RL("s35","47") FM("v79","s27","v51") \
 RL("s20","48") FM("v76","s28","v52") \
 RL("s21","49") FM("v77","s29","v53") \
 RL("s22","50") FM("v78","s30","v54") \
 RL("s23","51") FM("v79","s31","v55") \
 RL("s24","52") FM("v76","s32","v56") \
 RL("s25","53") FM("v77","s33","v57") \
 RL("s26","54") FM("v78","s34","v58") \
 RL("s27","55") FM("v79","s35","v59") \
 RL("s28","56") FM("v76","s20","v60") \
 RL("s29","57") FM("v77","s21","v61") \
 RL("s30","58") FM("v78","s22","v62") \
 RL("s31","59") FM("v79","s23","v63") \
 RL("s32","60") FM("v76","s24","v64") \
 RL("s33","61") FM("v77","s25","v65") \
 RL("s34","62") FM("v78","s26","v66") \
 RL("s35","63") FM("v79","s27","v67") \
 FM("v76","s28","v68") FM("v77","s29","v69") \
 FM("v78","s30","v70") FM("v79","s31","v71") \
 FM("v76","s32","v72") FM("v77","s33","v73") \
 FM("v78","s34","v74") FM("v79","s35","v75")

// combine 4 chains + relu -> h (v80)
#define HFIN \
 "v_add_f32 v76, v76, v77\n\t" \
 "v_add_f32 v78, v78, v79\n\t" \
 "v_add_f32 v76, v76, v78\n\t" \
 "v_max_f32 v80, 0, v76\n\t"

// Even step: consume x pair A (v82:83), prefetch t+2 into A.
// v86 = byte offset of the pair being prefetched; clamp keeps it in-bounds
// (clamped prefetches are never consumed).
#define STEP_EVEN \
 "s_waitcnt vmcnt(1)\n\t" \
 "v_mul_f32 v76, v82, v90\n\t" \
 "v_fmac_f32 v76, v83, v91\n\t" \
 "v_add_u32 v86, 16, v86\n\t" \
 "v_min_u32 v86, 0x3ff0, v86\n\t" \
 "global_load_dwordx2 v[82:83], v86, %[xb]\n\t" \
 MACBLOCK HFIN

// Odd step: consume x pair B (v84:85), prefetch t+3 into B (same v86, +8).
#define STEP_ODD \
 "s_waitcnt vmcnt(1)\n\t" \
 "v_mul_f32 v76, v84, v90\n\t" \
 "v_fmac_f32 v76, v85, v91\n\t" \
 "global_load_dwordx2 v[84:85], v86, %[xb] offset:8\n\t" \
 MACBLOCK HFIN

__global__ __launch_bounds__(64, 1) void rnn_scan_kernel(
    const float* __restrict__ x,    // [B, T, 2]
    const float* __restrict__ Wh,   // [64, 64] row-major
    const float* __restrict__ Wx,   // [64, 2]
    float* __restrict__ out)        // [B]
{
    const int b = blockIdx.x;
    const int j = threadIdx.x;   // 0..63, lane == hidden index

    const float* xb = x + (size_t)b * TT * II;

    float h;
    asm volatile(
        // ---- prologue: w row j -> v12..v75, wx row -> v90:91, x prefetch ----
        "v_lshlrev_b32 v87, 8, %[lane]\n\t"            // j*256 (row byte offset)
        "global_load_dwordx4 v[12:15], v87, %[wh]\n\t"
        "global_load_dwordx4 v[16:19], v87, %[wh] offset:16\n\t"
        "global_load_dwordx4 v[20:23], v87, %[wh] offset:32\n\t"
        "global_load_dwordx4 v[24:27], v87, %[wh] offset:48\n\t"
        "global_load_dwordx4 v[28:31], v87, %[wh] offset:64\n\t"
        "global_load_dwordx4 v[32:35], v87, %[wh] offset:80\n\t"
        "global_load_dwordx4 v[36:39], v87, %[wh] offset:96\n\t"
        "global_load_dwordx4 v[40:43], v87, %[wh] offset:112\n\t"
        "global_load_dwordx4 v[44:47], v87, %[wh] offset:128\n\t"
        "global_load_dwordx4 v[48:51], v87, %[wh] offset:144\n\t"
        "global_load_dwordx4 v[52:55], v87, %[wh] offset:160\n\t"
        "global_load_dwordx4 v[56:59], v87, %[wh] offset:176\n\t"
        "global_load_dwordx4 v[60:63], v87, %[wh] offset:192\n\t"
        "global_load_dwordx4 v[64:67], v87, %[wh] offset:208\n\t"
        "global_load_dwordx4 v[68:71], v87, %[wh] offset:224\n\t"
        "global_load_dwordx4 v[72:75], v87, %[wh] offset:240\n\t"
        "v_lshlrev_b32 v88, 3, %[lane]\n\t"            // j*8
        "global_load_dwordx2 v[90:91], v88, %[wx]\n\t"
        "v_mov_b32 v86, 0\n\t"
        "global_load_dwordx2 v[82:83], v86, %[xb]\n\t"           // x(t=0)
        "global_load_dwordx2 v[84:85], v86, %[xb] offset:8\n\t"  // x(t=1)
        "v_mov_b32 v80, 0\n\t"                          // h = 0
        "v_mov_b32 v88, 0\n\t"                          // pair counter
        "s_waitcnt vmcnt(0)\n\t"
        // ---- main loop: 1024 pairs of steps ----
        "LTOP_%=:\n\t"
        STEP_EVEN
        STEP_ODD
        "v_add_u32 v88, 1, v88\n\t"
        "v_cmp_gt_u32 vcc, 0x400, v88\n\t"
        "s_nop 1\n\t"
        "s_cbranch_vccnz LTOP_%=\n\t"
        // ---- epilogue: drain dangling prefetches, export h ----
        "s_waitcnt vmcnt(0)\n\t"
        "v_mov_b32 %[h], v80\n\t"
        : [h] "=&v"(h)
        : [lane] "v"(j), [wh] "s"(Wh), [xb] "s"(xb), [wx] "s"(Wx)
        : "memory", "vcc",
          "v12","v13","v14","v15","v16","v17","v18","v19",
          "v20","v21","v22","v23","v24","v25","v26","v27",
          "v28","v29","v30","v31","v32","v33","v34","v35",
          "v36","v37","v38","v39","v40","v41","v42","v43",
          "v44","v45","v46","v47","v48","v49","v50","v51",
          "v52","v53","v54","v55","v56","v57","v58","v59",
          "v60","v61","v62","v63","v64","v65","v66","v67",
          "v68","v69","v70","v71","v72","v73","v74","v75",
          "v76","v77","v78","v79","v80","v81","v82","v83",
          "v84","v85","v86","v87","v88","v89","v90","v91",
          "s20","s21","s22","s23","s24","s25","s26","s27",
          "s28","s29","s30","s31","s32","s33","s34","s35");

    // ||h_T||_2 across the wave
    float s = h * h;
#pragma unroll
    for (int off = 32; off > 0; off >>= 1)
        s += __shfl_xor(s, off, 64);
    if (j == 0)
        out[b] = sqrtf(s);
}

extern "C" void kernel_launch(void* const* d_in, const int* in_sizes, int n_in,
                              void* d_out, int out_size, void* d_ws, size_t ws_size,
                              hipStream_t stream) {
    const float* x  = (const float*)d_in[0];   // [B,T,2]
    const float* Wh = (const float*)d_in[1];   // [64,64]
    const float* Wx = (const float*)d_in[2];   // [64,2]
    float* out = (float*)d_out;                // [B]

    rnn_scan_kernel<<<dim3(BB), dim3(64), 0, stream>>>(x, Wh, Wx, out);
}

// Round 4
// 384.935 us; speedup vs baseline: 1.4313x; 1.4313x over previous
//
#include <hip/hip_runtime.h>
#include <math.h>

// Problem constants (match reference)
#define BB 1024
#define TT 2048
#define II 2
#define HH 64

// ---- DPP MAC building blocks ----------------------------------------------
// acc += c[row*16+r] * w   with DPP row_newbcast:r broadcasting lane r of each
// 16-lane row of c. No SGPRs involved -> no VALU->SGPR hazard stalls.
#define FM(a,c,w,r) "v_fmac_f32 " a ", " c ", " w " row_newbcast:" r "\n\t"
#define MU(a,c,w,r) "v_mul_f32 "  a ", " c ", " w " row_newbcast:" r "\n\t"

// Quarter x consumes copy c_x[l] = h[l ^ 16x]; row g thus sees h[16(g^x)+r]
// at bcast r, matched by weight reg v(12+16x+r) = W[j][16(g^x)+r] (weights
// loaded column-permuted per lane in the prologue). k-order differs per row;
// fp-sum reordering is safe (absmax stayed 0.0 across reorderings).
#define Q0 \
 FM("v76","v80","v12","0")  MU("v77","v80","v13","1")  MU("v78","v80","v14","2")  MU("v79","v80","v15","3") \
 FM("v76","v80","v16","4")  FM("v77","v80","v17","5")  FM("v78","v80","v18","6")  FM("v79","v80","v19","7") \
 FM("v76","v80","v20","8")  FM("v77","v80","v21","9")  FM("v78","v80","v22","10") FM("v79","v80","v23","11") \
 FM("v76","v80","v24","12") FM("v77","v80","v25","13") FM("v78","v80","v26","14") FM("v79","v80","v27","15")
#define Q1 \
 FM("v76","v81","v28","0")  FM("v77","v81","v29","1")  FM("v78","v81","v30","2")  FM("v79","v81","v31","3") \
 FM("v76","v81","v32","4")  FM("v77","v81","v33","5")  FM("v78","v81","v34","6")  FM("v79","v81","v35","7") \
 FM("v76","v81","v36","8")  FM("v77","v81","v37","9")  FM("v78","v81","v38","10") FM("v79","v81","v39","11") \
 FM("v76","v81","v40","12") FM("v77","v81","v41","13") FM("v78","v81","v42","14") FM("v79","v81","v43","15")
#define Q2 \
 FM("v76","v82","v44","0")  FM("v77","v82","v45","1")  FM("v78","v82","v46","2")  FM("v79","v82","v47","3") \
 FM("v76","v82","v48","4")  FM("v77","v82","v49","5")  FM("v78","v82","v50","6")  FM("v79","v82","v51","7") \
 FM("v76","v82","v52","8")  FM("v77","v82","v53","9")  FM("v78","v82","v54","10") FM("v79","v82","v55","11") \
 FM("v76","v82","v56","12") FM("v77","v82","v57","13") FM("v78","v82","v58","14") FM("v79","v82","v59","15")
#define Q3 \
 FM("v76","v83","v60","0")  FM("v77","v83","v61","1")  FM("v78","v83","v62","2")  FM("v79","v83","v63","3") \
 FM("v76","v83","v64","4")  FM("v77","v83","v65","5")  FM("v78","v83","v66","6")  FM("v79","v83","v67","7") \
 FM("v76","v83","v68","8")  FM("v77","v83","v69","9")  FM("v78","v83","v70","10") FM("v79","v83","v71","11") \
 FM("v76","v83","v72","12") FM("v77","v83","v73","13") FM("v78","v83","v74","14") FM("v79","v83","v75","15")

// combine 4 chains + relu -> h (v80)
#define HFIN \
 "v_add_f32 v76, v76, v77\n\t" \
 "v_add_f32 v78, v78, v79\n\t" \
 "v_add_f32 v76, v76, v78\n\t" \
 "v_max_f32 v80, 0, v76\n\t"

// Shared step body after the x-specific init: build copies c1..c3 and run
// the 4 MAC quarters. c1 = h^16 (ds_swizzle xor16), c2 = h^32 (ds_bpermute,
// vaddr v89 = (lane^32)*4), c3 = c2^16. Shuffle latency hides under Q0/Q1.
#define MACS \
 Q0 \
 "s_waitcnt lgkmcnt(0)\n\t" \
 "ds_swizzle_b32 v83, v82 offset:0x401f\n\t" \
 "s_nop 1\n\t" \
 Q1 \
 "s_waitcnt lgkmcnt(0)\n\t" \
 "s_nop 1\n\t" \
 Q2 \
 Q3 \
 HFIN

// Even step: consume x pair A (v84:85), advance+clamp offset, prefetch into A.
#define STEP_EVEN \
 "ds_swizzle_b32 v81, v80 offset:0x401f\n\t" \
 "ds_bpermute_b32 v82, v89, v80\n\t" \
 "s_waitcnt vmcnt(1)\n\t" \
 "v_mul_f32 v76, v84, v90\n\t" \
 "v_fmac_f32 v76, v85, v91\n\t" \
 "v_add_u32 v88, 16, v88\n\t" \
 "v_min_u32 v88, 0x3ff0, v88\n\t" \
 "global_load_dwordx2 v[84:85], v88, %[xb]\n\t" \
 MACS

// Odd step: consume x pair B (v86:87), prefetch into B at offset+8.
#define STEP_ODD \
 "ds_swizzle_b32 v81, v80 offset:0x401f\n\t" \
 "ds_bpermute_b32 v82, v89, v80\n\t" \
 "s_waitcnt vmcnt(1)\n\t" \
 "v_mul_f32 v76, v86, v90\n\t" \
 "v_fmac_f32 v76, v87, v91\n\t" \
 "global_load_dwordx2 v[86:87], v88, %[xb] offset:8\n\t" \
 MACS

__global__ __launch_bounds__(64, 1) void rnn_scan_kernel(
    const float* __restrict__ x,    // [B, T, 2]
    const float* __restrict__ Wh,   // [64, 64] row-major
    const float* __restrict__ Wx,   // [64, 2]
    float* __restrict__ out)        // [B]
{
    const int b = blockIdx.x;
    const int j = threadIdx.x;   // 0..63, lane == hidden index

    const float* xb = x + (size_t)b * TT * II;

    float h;
    asm volatile(
        // ---- prologue ------------------------------------------------------
        // Column-permuted weight load: w reg v(12+16x+r) = W[j][16((j>>4)^x)+r]
        "v_lshlrev_b32 v92, 8, %[lane]\n\t"        // j*256
        "v_lshrrev_b32 v93, 4, %[lane]\n\t"        // g = j>>4
        "v_lshlrev_b32 v89, 6, v93\n\t"            // (g^0)*64
        "v_add_u32 v89, v92, v89\n\t"
        "global_load_dwordx4 v[12:15], v89, %[wh]\n\t"
        "global_load_dwordx4 v[16:19], v89, %[wh] offset:16\n\t"
        "global_load_dwordx4 v[20:23], v89, %[wh] offset:32\n\t"
        "global_load_dwordx4 v[24:27], v89, %[wh] offset:48\n\t"
        "v_xor_b32 v89, 1, v93\n\t"
        "v_lshlrev_b32 v89, 6, v89\n\t"            // (g^1)*64
        "v_add_u32 v89, v92, v89\n\t"
        "global_load_dwordx4 v[28:31], v89, %[wh]\n\t"
        "global_load_dwordx4 v[32:35], v89, %[wh] offset:16\n\t"
        "global_load_dwordx4 v[36:39], v89, %[wh] offset:32\n\t"
        "global_load_dwordx4 v[40:43], v89, %[wh] offset:48\n\t"
        "v_xor_b32 v89, 2, v93\n\t"
        "v_lshlrev_b32 v89, 6, v89\n\t"            // (g^2)*64
        "v_add_u32 v89, v92, v89\n\t"
        "global_load_dwordx4 v[44:47], v89, %[wh]\n\t"
        "global_load_dwordx4 v[48:51], v89, %[wh] offset:16\n\t"
        "global_load_dwordx4 v[52:55], v89, %[wh] offset:32\n\t"
        "global_load_dwordx4 v[56:59], v89, %[wh] offset:48\n\t"
        "v_xor_b32 v89, 3, v93\n\t"
        "v_lshlrev_b32 v89, 6, v89\n\t"            // (g^3)*64
        "v_add_u32 v89, v92, v89\n\t"
        "global_load_dwordx4 v[60:63], v89, %[wh]\n\t"
        "global_load_dwordx4 v[64:67], v89, %[wh] offset:16\n\t"
        "global_load_dwordx4 v[68:71], v89, %[wh] offset:32\n\t"
        "global_load_dwordx4 v[72:75], v89, %[wh] offset:48\n\t"
        // wx row j -> v90:91
        "v_lshlrev_b32 v89, 3, %[lane]\n\t"
        "global_load_dwordx2 v[90:91], v89, %[wx]\n\t"
        // x prefetch: pair A = x(t=0), pair B = x(t=1)
        "v_mov_b32 v88, 0\n\t"
        "global_load_dwordx2 v[84:85], v88, %[xb]\n\t"
        "global_load_dwordx2 v[86:87], v88, %[xb] offset:8\n\t"
        // bpermute address for lane^32, h init, loop counter
        "v_xor_b32 v89, 32, %[lane]\n\t"
        "v_lshlrev_b32 v89, 2, v89\n\t"
        "v_mov_b32 v80, 0\n\t"
        "s_movk_i32 s16, 0x400\n\t"
        "s_waitcnt vmcnt(0)\n\t"
        // ---- main loop: 1024 pairs of steps --------------------------------
        "LTOP_%=:\n\t"
        STEP_EVEN
        STEP_ODD
        "s_sub_u32 s16, s16, 1\n\t"
        "s_cmp_lg_u32 s16, 0\n\t"
        "s_cbranch_scc1 LTOP_%=\n\t"
        // ---- epilogue ------------------------------------------------------
        "s_waitcnt vmcnt(0)\n\t"
        "v_mov_b32 %[h], v80\n\t"
        : [h] "=&v"(h)
        : [lane] "v"(j), [wh] "s"(Wh), [xb] "s"(xb), [wx] "s"(Wx)
        : "memory", "scc",
          "v12","v13","v14","v15","v16","v17","v18","v19",
          "v20","v21","v22","v23","v24","v25","v26","v27",
          "v28","v29","v30","v31","v32","v33","v34","v35",
          "v36","v37","v38","v39","v40","v41","v42","v43",
          "v44","v45","v46","v47","v48","v49","v50","v51",
          "v52","v53","v54","v55","v56","v57","v58","v59",
          "v60","v61","v62","v63","v64","v65","v66","v67",
          "v68","v69","v70","v71","v72","v73","v74","v75",
          "v76","v77","v78","v79","v80","v81","v82","v83",
          "v84","v85","v86","v87","v88","v89","v90","v91",
          "v92","v93",
          "s16");

    // ||h_T||_2 across the wave
    float s = h * h;
#pragma unroll
    for (int off = 32; off > 0; off >>= 1)
        s += __shfl_xor(s, off, 64);
    if (j == 0)
        out[b] = sqrtf(s);
}

extern "C" void kernel_launch(void* const* d_in, const int* in_sizes, int n_in,
                              void* d_out, int out_size, void* d_ws, size_t ws_size,
                              hipStream_t stream) {
    const float* x  = (const float*)d_in[0];   // [B,T,2]
    const float* Wh = (const float*)d_in[1];   // [64,64]
    const float* Wx = (const float*)d_in[2];   // [64,2]
    float* out = (float*)d_out;                // [B]

    rnn_scan_kernel<<<dim3(BB), dim3(64), 0, stream>>>(x, Wh, Wx, out);
}